// Round 3
// baseline (199.205 us; speedup 1.0000x reference)
//
#include <hip/hip_runtime.h>
#include <hip/hip_bf16.h>

// Problem constants
#define BSZ 64
#define LL  64
#define SS  63
#define AMB 32
#define HH  128
#define EE  300
#define MLPN 1024
#define GG  640      // 5*H
#define K2  256      // 2*H
#define PP  127      // L+S
#define CROW 272     // chart LDS row stride in shorts (544 B; 16B-aligned rows)

typedef __attribute__((ext_vector_type(8))) short short8;   // 8 bf16 MFMA A/B frag
typedef __attribute__((ext_vector_type(4))) float f32x4;

__device__ __forceinline__ float sigf(float x) { return 1.f / (1.f + __expf(-x)); }

__device__ __forceinline__ unsigned short f2bf(float x) {
    unsigned int u = __float_as_uint(x);
    u += 0x7fffu + ((u >> 16) & 1u);      // RNE
    return (unsigned short)(u >> 16);
}
__device__ __forceinline__ float bf2f(short x) {
    return __uint_as_float(((unsigned)(unsigned short)x) << 16);
}

__device__ __forceinline__ short8 cvt8(f32x4 x0, f32x4 x1) {
    short8 v;
    v[0]=(short)f2bf(x0[0]); v[1]=(short)f2bf(x0[1]);
    v[2]=(short)f2bf(x0[2]); v[3]=(short)f2bf(x0[3]);
    v[4]=(short)f2bf(x1[0]); v[5]=(short)f2bf(x1[1]);
    v[6]=(short)f2bf(x1[2]); v[7]=(short)f2bf(x1[3]);
    return v;
}

// ---------------------------------------------------------------------------
// Leaf kernel: 256 blocks x 1024 threads (all 256 CUs). Block = (pair, half):
// gathers 32 token embeddings, computes 32 leaf rows (gates i,o,u) via MFMA,
// converting W f32->bf16 B-fragments INLINE (W is 0.77 MB, L2-resident;
// conversion is free VALU at 4.5% VALUBusy). No prep kernel, no WTB.
// B-frag layout for mfma_f32_16x16x32_bf16: g = tile*16 + (lane&15),
// k = kk*32 + (lane>>4)*8 + j.
// ---------------------------------------------------------------------------
__global__ void __launch_bounds__(1024, 4) leaf_kernel(
        const int* __restrict__ sent1, const int* __restrict__ sent2,
        const float* __restrict__ W, const float* __restrict__ bias,
        const float* __restrict__ unk, const float* __restrict__ wemb,
        short* __restrict__ chartG) {
    __shared__ __align__(16) short AsL[2 * 10 * 64 * 8];   // 20 KiB A-frags
    const int tid = threadIdx.x;
    const int blk = blockIdx.x, pair = blk >> 1, half = blk & 1;
    const int ch = pair >> 6, b = pair & 63;
    const int* sent = ch ? sent2 : sent1;
    const int w = tid >> 6, lane = tid & 63, quad = lane >> 4, l15 = lane & 15;

    // ---- embedding gather: 32 tokens x 40 k-octets = 1280 slots ----
    {
        float ef[2][8];
        int est[2], eso[2];
#pragma unroll
        for (int i = 0; i < 2; ++i) {
            int slot = i * 1024 + tid;
            est[i] = -1;
            if (slot < 1280) {
                int tloc = slot / 40, oct = slot - tloc * 40;
                est[i] = tloc; eso[i] = oct;
                int sid = sent[b * LL + half * 32 + tloc];   // direct, L1-broadcast
                const float* src = (sid >= 0) ? (wemb + (size_t)sid * EE) : unk;
                int k0 = oct * 8;
                if (k0 + 8 <= EE) {
                    f32x4 x0 = *(const f32x4*)(src + k0);
                    f32x4 x1 = *(const f32x4*)(src + k0 + 4);
                    ef[i][0]=x0[0]; ef[i][1]=x0[1]; ef[i][2]=x0[2]; ef[i][3]=x0[3];
                    ef[i][4]=x1[0]; ef[i][5]=x1[1]; ef[i][6]=x1[2]; ef[i][7]=x1[3];
                } else {
#pragma unroll
                    for (int j = 0; j < 8; ++j) ef[i][j] = (k0 + j < EE) ? src[k0 + j] : 0.f;
                }
            }
        }
#pragma unroll
        for (int i = 0; i < 2; ++i) {
            if (est[i] >= 0) {
                int tloc = est[i], oct = eso[i];
                short8 v;
#pragma unroll
                for (int j = 0; j < 8; ++j) v[j] = (short)f2bf(ef[i][j]);
                *(short8*)(AsL + (((tloc >> 4) * 10 + (oct >> 2)) * 64
                                  + ((oct & 3) << 4) + (tloc & 15)) * 8) = v;
            }
        }
    }
    __syncthreads();

    // ---- leaf GEMM: wave = (mt2, nu); B tiles {nu, nu+24, nu+32} = i,o,u ----
    const int mt2 = w & 1, nu = w >> 1;
    const int koff = quad << 3;
    const float* Wr0 = W + (size_t)(nu * 16 + l15) * EE;          // i-gate row
    const float* Wr1 = W + (size_t)((nu + 24) * 16 + l15) * EE;   // o-gate row
    const float* Wr2 = W + (size_t)((nu + 32) * 16 + l15) * EE;   // u-gate row
    f32x4 acc[3] = {};
#pragma unroll 2
    for (int kk = 0; kk < 10; ++kk) {
        short8 a0 = *(const short8*)(AsL + ((mt2 * 10 + kk) * 64 + lane) * 8);
        int k0 = kk * 32 + koff;
        short8 b0, b1, b2;
        if (k0 + 8 <= EE) {
            b0 = cvt8(*(const f32x4*)(Wr0 + k0), *(const f32x4*)(Wr0 + k0 + 4));
            b1 = cvt8(*(const f32x4*)(Wr1 + k0), *(const f32x4*)(Wr1 + k0 + 4));
            b2 = cvt8(*(const f32x4*)(Wr2 + k0), *(const f32x4*)(Wr2 + k0 + 4));
        } else {
#pragma unroll
            for (int j = 0; j < 8; ++j) {
                float f0 = 0.f, f1 = 0.f, f2 = 0.f;
                if (k0 + j < EE) { f0 = Wr0[k0 + j]; f1 = Wr1[k0 + j]; f2 = Wr2[k0 + j]; }
                b0[j] = (short)f2bf(f0); b1[j] = (short)f2bf(f1); b2[j] = (short)f2bf(f2);
            }
        }
        acc[0] = __builtin_amdgcn_mfma_f32_16x16x32_bf16(a0, b0, acc[0], 0, 0, 0);
        acc[1] = __builtin_amdgcn_mfma_f32_16x16x32_bf16(a0, b1, acc[1], 0, 0, 0);
        acc[2] = __builtin_amdgcn_mfma_f32_16x16x32_bf16(a0, b2, acc[2], 0, 0, 0);
    }

    {
        int jc = nu * 16 + l15;
        float bi = bias[jc], bo = bias[3 * HH + jc], bu = bias[4 * HH + jc];
        size_t pb = (size_t)pair * 16384;    // 64 rows * 256
#pragma unroll
        for (int r = 0; r < 4; ++r) {
            float cv = sigf(acc[0][r] + bi) * tanhf(acc[2][r] + bu);
            float hv = sigf(acc[1][r] + bo) * tanhf(cv);
            int l = half * 32 + mt2 * 16 + quad * 4 + r;
            chartG[pb + (size_t)l * 256 + jc]      = (short)f2bf(cv);
            chartG[pb + (size_t)l * 256 + HH + jc] = (short)f2bf(hv);
        }
    }
}

// ---------------------------------------------------------------------------
// Step kernel: 128 blocks x 1024 threads, one (chart,batch) pair per block.
// All global loads issued up front; liveness masks built from the loaded
// registers (16-lane segmented shfl-OR, no extra LDS pass); transitive
// closure is a wave-parallel fixed-point (1 round when no step references
// another step). U f32->bf16 B-frags converted inline (no UTB/prep).
// ---------------------------------------------------------------------------
__global__ void __launch_bounds__(1024, 4) step_kernel(
        const int* __restrict__ ops1, const int* __restrict__ ops2,
        const int* __restrict__ oopl1, const int* __restrict__ oopl2,
        const float* __restrict__ U, const float* __restrict__ bias,
        const float* __restrict__ eu, const float* __restrict__ invt,
        const short* __restrict__ chartG, float* __restrict__ fin) {
    __shared__ __align__(16) short chartL[127 * CROW + 16];   // 69.1 KiB bf16 chart
    __shared__ __align__(16) short As2[2 * 8 * 64 * 8];       // 16 KiB step A-frags
    __shared__ __align__(16) float chh[32 * 132];             // 16.9 KiB
    __shared__ __align__(16) int ops_all[SS * 64];            // 16.1 KiB
    __shared__ unsigned long long smask[64];
    __shared__ int live_list[SS];
    __shared__ float e_num[AMB], h2s[AMB], s_w[AMB];
    __shared__ float comb[2][2][HH];
    __shared__ int nl_sh;
    __shared__ float un_sh;

    const int tid = threadIdx.x;
    const int pair = blockIdx.x, ch = pair >> 6, b = pair & 63;
    const int* ops  = ch ? ops2 : ops1;
    const int* oopl = ch ? oopl2 : oopl1;
    const float it = invt[0];
    const int w = tid >> 6, lane = tid & 63, quad = lane >> 4, l15 = lane & 15;

    // ---- issue ALL independent global loads up front ----
    const int4* cg = (const int4*)(chartG + (size_t)pair * 16384);
    int4 c0 = cg[tid];
    int4 c1 = cg[1024 + tid];
    int4 opv = make_int4(0, 0, 0, 0);
    if (tid < 1008) opv = ((const int4*)(ops + (size_t)b * SS * 64))[tid];
    if (tid < 64) {
        float v = eu[tid] * eu[tid] + eu[tid + 64] * eu[tid + 64];
        for (int off = 32; off >= 1; off >>= 1) v += __shfl_xor(v, off);
        if (tid == 0) un_sh = fmaxf(sqrtf(v), 1e-8f);
    }
    // zero step rows (independent of loads)
#pragma unroll
    for (int i = 0; i < 3; ++i) {
        int idx = i * 1024 + tid;
        if (idx < 2142)   // 63 rows x 272 shorts = 2142 int4
            ((int4*)(chartL + 64 * CROW))[idx] = make_int4(0, 0, 0, 0);
    }
    // store leaf rows into LDS chart (row stride CROW)
    {
        int r0 = tid >> 5, cq0 = tid & 31;
        *(int4*)(chartL + r0 * CROW + (cq0 << 3)) = c0;
        int t2 = 1024 + tid;
        int r1 = t2 >> 5, cq1 = t2 & 31;
        *(int4*)(chartL + r1 * CROW + (cq1 << 3)) = c1;
    }
    // clamp + store ops; build per-step masks from registers
    {
        opv.x = min(max(opv.x, 0), PP - 1);
        opv.y = min(max(opv.y, 0), PP - 1);
        opv.z = min(max(opv.z, 0), PP - 1);
        opv.w = min(max(opv.w, 0), PP - 1);
        if (tid < 1008) ((int4*)ops_all)[tid] = opv;

        int t = tid >> 4;            // 16 threads (one int4 each) per step row
        unsigned long long bit = 0ull;
        if (tid < 1008) {
            int q;
            q = opv.x - LL; if (q >= 0 && q < t) bit |= 1ull << q;
            q = opv.y - LL; if (q >= 0 && q < t) bit |= 1ull << q;
            q = opv.z - LL; if (q >= 0 && q < t) bit |= 1ull << q;
            q = opv.w - LL; if (q >= 0 && q < t) bit |= 1ull << q;
        }
        bit |= __shfl_xor(bit, 1);
        bit |= __shfl_xor(bit, 2);
        bit |= __shfl_xor(bit, 4);
        bit |= __shfl_xor(bit, 8);
        if ((lane & 15) == 0 && t < SS) smask[t] = bit;
    }
    __syncthreads();

    // ---- wave-parallel transitive closure (wave 0) ----
    if (w == 0) {
        unsigned long long my = (lane < SS) ? smask[lane] : 0ull;
        unsigned long long m = 0ull;
        int q0 = oopl[b] - 1 - LL;
        if (q0 >= 0) { if (q0 > SS - 1) q0 = SS - 1; m = 1ull << q0; }
        while (true) {
            unsigned long long c = ((m >> lane) & 1ull) ? my : 0ull;
            for (int off = 32; off >= 1; off >>= 1) c |= __shfl_xor(c, off);
            unsigned long long nm = m | c;
            if (nm == m) break;
            m = nm;
        }
        if (lane == 0) {
            int n = 0;
            for (int t = 0; t < SS; ++t)
                if ((m >> t) & 1) live_list[n++] = t;
            nl_sh = n;
        }
    }
    __syncthreads();

    // ---- live steps (all LDS; U B-frags converted inline from f32) ----
    const int nl = nl_sh;
    const float eul = eu[lane], euh = eu[64 + lane];
    const int smt = w & 1, snu = w >> 1;
    const int sjc = snu * 16 + l15;
    const float bi  = bias[sjc],          bfl = bias[HH + sjc];
    const float bfr = bias[2 * HH + sjc], bo  = bias[3 * HH + sjc];
    const float bu  = bias[4 * HH + sjc];
    const int ukoff = quad << 3;
    const float* Ur0 = U + (size_t)((snu +  0) * 16 + l15) * K2;  // i
    const float* Ur1 = U + (size_t)((snu +  8) * 16 + l15) * K2;  // fL
    const float* Ur2 = U + (size_t)((snu + 16) * 16 + l15) * K2;  // fR
    const float* Ur3 = U + (size_t)((snu + 24) * 16 + l15) * K2;  // o
    const float* Ur4 = U + (size_t)((snu + 32) * 16 + l15) * K2;  // u

    for (int sidx = 0; sidx < nl; ++sidx) {
        const int t = live_list[sidx];
        const int* oprow = ops_all + t * 64;

        // gather h -> step A-frags (pure LDS->LDS b128)
        {
            int a = tid >> 5, oct = tid & 31, side = oct >> 4, m8 = oct & 15;
            int row = oprow[2 * a + side];
            short8 v = *(const short8*)(chartL + row * CROW + HH + m8 * 8);
            *(short8*)(As2 + (((a >> 4) * 8 + (oct >> 2)) * 64
                              + ((oct & 3) << 4) + (a & 15)) * 8) = v;
        }
        __syncthreads();

        float cvals[4], hvals[4];
        {
            f32x4 acc[5] = {};
#pragma unroll 2
            for (int kk = 0; kk < 8; ++kk) {
                short8 a0 = *(const short8*)(As2 + ((smt * 8 + kk) * 64 + lane) * 8);
                int k0 = kk * 32 + ukoff;
                short8 b0 = cvt8(*(const f32x4*)(Ur0 + k0), *(const f32x4*)(Ur0 + k0 + 4));
                short8 b1 = cvt8(*(const f32x4*)(Ur1 + k0), *(const f32x4*)(Ur1 + k0 + 4));
                short8 b2 = cvt8(*(const f32x4*)(Ur2 + k0), *(const f32x4*)(Ur2 + k0 + 4));
                short8 b3 = cvt8(*(const f32x4*)(Ur3 + k0), *(const f32x4*)(Ur3 + k0 + 4));
                short8 b4 = cvt8(*(const f32x4*)(Ur4 + k0), *(const f32x4*)(Ur4 + k0 + 4));
                acc[0] = __builtin_amdgcn_mfma_f32_16x16x32_bf16(a0, b0, acc[0], 0, 0, 0);
                acc[1] = __builtin_amdgcn_mfma_f32_16x16x32_bf16(a0, b1, acc[1], 0, 0, 0);
                acc[2] = __builtin_amdgcn_mfma_f32_16x16x32_bf16(a0, b2, acc[2], 0, 0, 0);
                acc[3] = __builtin_amdgcn_mfma_f32_16x16x32_bf16(a0, b3, acc[3], 0, 0, 0);
                acc[4] = __builtin_amdgcn_mfma_f32_16x16x32_bf16(a0, b4, acc[4], 0, 0, 0);
            }
#pragma unroll
            for (int r = 0; r < 4; ++r) {
                int a = smt * 16 + quad * 4 + r;
                float ccLv = bf2f(chartL[oprow[2 * a] * CROW + sjc]);
                float ccRv = bf2f(chartL[oprow[2 * a + 1] * CROW + sjc]);
                float cv = sigf(acc[1][r] + bfl) * ccLv
                         + sigf(acc[2][r] + bfr) * ccRv
                         + sigf(acc[0][r] + bi) * tanhf(acc[4][r] + bu);
                float hv = sigf(acc[3][r] + bo) * tanhf(cv);
                cvals[r] = cv; hvals[r] = hv;
                chh[a * 132 + sjc] = hv;
            }
        }
        __syncthreads();

        // energy per candidate (16 waves x 2 cands)
#pragma unroll
        for (int i = 0; i < 2; ++i) {
            int a = w * 2 + i;
            float h0 = chh[a * 132 + lane], h1 = chh[a * 132 + 64 + lane];
            float pe = h0 * eul + h1 * euh;
            float pn = h0 * h0 + h1 * h1;
            for (int off = 32; off >= 1; off >>= 1) {
                pe += __shfl_xor(pe, off);
                pn += __shfl_xor(pn, off);
            }
            if (lane == 0) { e_num[a] = pe; h2s[a] = pn; }
        }
        __syncthreads();

        // softmax over 32 candidates (wave 0)
        if (tid < 64) {
            float v = (tid < AMB)
                ? (e_num[tid] / (fmaxf(sqrtf(h2s[tid]), 1e-8f) * un_sh)) * it
                : -3.4e38f;
            float m = v;
            for (int off = 32; off >= 1; off >>= 1) m = fmaxf(m, __shfl_xor(m, off));
            float ex = (tid < AMB) ? __expf(v - m) : 0.f;
            float su = ex;
            for (int off = 32; off >= 1; off >>= 1) su += __shfl_xor(su, off);
            if (tid < AMB) s_w[tid] = ex / su;
        }
        __syncthreads();

        // combine from registers, reduce across quads, write chart row L+t
        {
            float sc = 0.f, sh = 0.f;
#pragma unroll
            for (int r = 0; r < 4; ++r) {
                int a = smt * 16 + quad * 4 + r;
                float sw = s_w[a];
                sc = fmaf(sw, cvals[r], sc);
                sh = fmaf(sw, hvals[r], sh);
            }
            sc += __shfl_xor(sc, 16); sc += __shfl_xor(sc, 32);
            sh += __shfl_xor(sh, 16); sh += __shfl_xor(sh, 32);
            if (lane < 16) {
                comb[smt][0][sjc] = sc;
                comb[smt][1][sjc] = sh;
            }
        }
        __syncthreads();
        if (tid < K2) {
            int part = tid >> 7, col = tid & 127;
            float val = comb[0][part][col] + comb[1][part][col];
            chartL[(LL + t) * CROW + part * HH + col] = (short)f2bf(val);
        }
        __syncthreads();
    }

    // ---- final readout row -> global ----
    int p = min(max(oopl[b] - 1, 0), PP - 1);
    if (tid < K2)
        fin[(size_t)pair * K2 + tid] = bf2f(chartL[p * CROW + tid]);
}

// ---------------------------------------------------------------------------
// MLP readout: 256 blocks = 16 j-tiles x 16 b-tiles (4 batch rows each).
// ---------------------------------------------------------------------------
__global__ void __launch_bounds__(256) mlp_kernel(
        const float* __restrict__ fin,
        const float* __restrict__ A, const float* __restrict__ abias,
        float* __restrict__ out) {
    __shared__ __align__(16) float conc[4][512];
    const int tid = threadIdx.x;
    const int jt = blockIdx.x & 15, bt = blockIdx.x >> 4;

#pragma unroll
    for (int i = 0; i < 2; ++i) {
        int s = i * 256 + tid;                // 512 vec4 slots = 4 b x 128
        int bl = s >> 7, kv = s & 127;
        int k0 = kv * 4, sel = k0 >> 7, kk0 = k0 & 127;
        int b = bt * 4 + bl;
        f32x4 s1 = *(const f32x4*)(fin + (size_t)b * K2 + HH + kk0);
        f32x4 s2 = *(const f32x4*)(fin + (size_t)(BSZ + b) * K2 + HH + kk0);
        f32x4 v;
        if (sel == 0)      { f32x4 d = s1 - s2; v = d * d; }
        else if (sel == 1) v = s1 * s2;
        else if (sel == 2) v = s1;
        else               v = s2;
        *(f32x4*)&conc[bl][k0] = v;
    }
    __syncthreads();

    const int jj = tid & 63, bg = tid >> 6;
    const int j = jt * 64 + jj, b = bt * 4 + bg;
    const float* Arow = A + (size_t)j * 512;
    float acc0 = abias[j], acc1 = 0.f;
    for (int k = 0; k < 512; k += 8) {
        f32x4 a0 = *(const f32x4*)(Arow + k);
        f32x4 a1 = *(const f32x4*)(Arow + k + 4);
        f32x4 c0 = *(const f32x4*)&conc[bg][k];
        f32x4 c1 = *(const f32x4*)&conc[bg][k + 4];
#pragma unroll
        for (int u = 0; u < 4; ++u) {
            acc0 = fmaf(a0[u], c0[u], acc0);
            acc1 = fmaf(a1[u], c1[u], acc1);
        }
    }
    out[(size_t)b * MLPN + j] = fmaxf(acc0 + acc1, 0.f);
}

// ---------------------------------------------------------------------------
extern "C" void kernel_launch(void* const* d_in, const int* in_sizes, int n_in,
                              void* d_out, int out_size, void* d_ws, size_t ws_size,
                              hipStream_t stream) {
    const int*   sent1 = (const int*)d_in[0];
    const int*   ops1  = (const int*)d_in[1];
    const int*   oopl1 = (const int*)d_in[2];
    const int*   sent2 = (const int*)d_in[3];
    const int*   ops2  = (const int*)d_in[4];
    const int*   oopl2 = (const int*)d_in[5];
    const float* W     = (const float*)d_in[6];
    const float* U     = (const float*)d_in[7];
    const float* bias  = (const float*)d_in[8];
    const float* eu    = (const float*)d_in[9];
    const float* unk   = (const float*)d_in[10];
    const float* wemb  = (const float*)d_in[11];
    const float* A     = (const float*)d_in[12];
    const float* ab    = (const float*)d_in[13];
    const float* invt  = (const float*)d_in[14];
    float* out = (float*)d_out;
    (void)in_sizes; (void)n_in; (void)out_size; (void)ws_size;

    char* ws = (char*)d_ws;
    // ws layout (bytes):
    const size_t CHG_OFF = 0;            // 128*64*256*2 = 4,194,304
    const size_t FIN_OFF = 4194304;      // 128*256*4 = 131,072  (end 4,325,376)
    short* chartG = (short*)(ws + CHG_OFF);
    float* fin    = (float*)(ws + FIN_OFF);

    // leaf phase on ALL 256 CUs (W converted inline; no prep kernel)
    leaf_kernel<<<256, 1024, 0, stream>>>(sent1, sent2, W, bias, unk, wemb, chartG);

    // step phase: 128 blocks (U converted inline)
    step_kernel<<<128, 1024, 0, stream>>>(ops1, ops2, oopl1, oopl2,
                                          U, bias, eu, invt, chartG, fin);

    mlp_kernel<<<256, 256, 0, stream>>>(fin, A, ab, out);
}

// Round 4
// 183.391 us; speedup vs baseline: 1.0862x; 1.0862x over previous
//
#include <hip/hip_runtime.h>
#include <hip/hip_bf16.h>

// Problem constants
#define BSZ 64
#define LL  64
#define SS  63
#define AMB 32
#define HH  128
#define EE  300
#define MLPN 1024
#define GG  640      // 5*H
#define K2  256      // 2*H
#define PP  127      // L+S
#define CROW 272     // chart LDS row stride in shorts (544 B; 16B-aligned rows)

typedef __attribute__((ext_vector_type(8))) short short8;   // 8 bf16 MFMA A/B frag
typedef __attribute__((ext_vector_type(4))) float f32x4;

__device__ __forceinline__ float sigf(float x) { return 1.f / (1.f + __expf(-x)); }

__device__ __forceinline__ unsigned short f2bf(float x) {
    unsigned int u = __float_as_uint(x);
    u += 0x7fffu + ((u >> 16) & 1u);      // RNE
    return (unsigned short)(u >> 16);
}
__device__ __forceinline__ float bf2f(short x) {
    return __uint_as_float(((unsigned)(unsigned short)x) << 16);
}

__device__ __forceinline__ short8 cvt8(f32x4 x0, f32x4 x1) {
    short8 v;
    v[0]=(short)f2bf(x0[0]); v[1]=(short)f2bf(x0[1]);
    v[2]=(short)f2bf(x0[2]); v[3]=(short)f2bf(x0[3]);
    v[4]=(short)f2bf(x1[0]); v[5]=(short)f2bf(x1[1]);
    v[6]=(short)f2bf(x1[2]); v[7]=(short)f2bf(x1[3]);
    return v;
}

// ---------------------------------------------------------------------------
// Prep: pack W -> WTB, U -> UTB as bf16 B-operand fragments of
// mfma_f32_16x16x32_bf16:
//   XTB[((n*KSTEPS + kk)*64 + lane)*8 + j] = X[g][k],
//   g = n*16 + (lane&15), k = kk*32 + (lane>>4)*8 + j
// COALESCED reads: thread handles one 8-f32 row chunk (consecutive threads =
// consecutive 32 B of the same weight row); the 16 B packed-fragment write is
// scattered but fire-and-forget (no latency chain). This avoids the 1.2 KB/
// lane row-stride fragmentation that made inline conversion transaction-bound.
// ---------------------------------------------------------------------------
#define PWT 25600    // 640 rows * 40 chunks (k padded 300->320, kk=9 zero-filled)
#define PUT 20480    // 640 rows * 32 chunks
__global__ void __launch_bounds__(256) prep_kernel(
        const float* __restrict__ W, const float* __restrict__ U,
        short* __restrict__ WTB, short* __restrict__ UTB) {
    int idx = blockIdx.x * 256 + threadIdx.x;
    if (idx < PWT) {
        int g = idx / 40, cc = idx - g * 40;
        int k0 = cc * 8;
        float f[8];
#pragma unroll
        for (int j = 0; j < 8; ++j)
            f[j] = (k0 + j < EE) ? W[(size_t)g * EE + k0 + j] : 0.f;
        short8 v;
#pragma unroll
        for (int j = 0; j < 8; ++j) v[j] = (short)f2bf(f[j]);
        int n = g >> 4, l15 = g & 15;
        int kk = k0 >> 5, quad = (k0 >> 3) & 3;
        *(short8*)(WTB + ((size_t)((n * 10 + kk) * 64 + quad * 16 + l15)) * 8) = v;
    } else if (idx < PWT + PUT) {
        int o = idx - PWT;
        int g = o >> 5, cc = o & 31;
        int k0 = cc * 8;
        f32x4 x0 = *(const f32x4*)(U + (size_t)g * K2 + k0);
        f32x4 x1 = *(const f32x4*)(U + (size_t)g * K2 + k0 + 4);
        int n = g >> 4, l15 = g & 15;
        int kk = k0 >> 5, quad = (k0 >> 3) & 3;
        *(short8*)(UTB + ((size_t)((n * 8 + kk) * 64 + quad * 16 + l15)) * 8) = cvt8(x0, x1);
    }
}

// ---------------------------------------------------------------------------
// Leaf kernel: 256 blocks x 1024 threads (all 256 CUs). Block = (pair, half):
// gathers 32 token embeddings, computes 32 leaf rows (gates i,o,u) via MFMA
// against packed WTB (lane-contiguous 16 B loads = fully coalesced),
// software-pipelined across k-steps. Writes bf16 c||h rows to global chart.
// ---------------------------------------------------------------------------
__global__ void __launch_bounds__(1024) leaf_kernel(
        const int* __restrict__ sent1, const int* __restrict__ sent2,
        const short* __restrict__ WTB, const float* __restrict__ bias,
        const float* __restrict__ unk, const float* __restrict__ wemb,
        short* __restrict__ chartG) {
    __shared__ __align__(16) short AsL[2 * 10 * 64 * 8];   // 20 KiB A-frags
    const int tid = threadIdx.x;
    const int blk = blockIdx.x, pair = blk >> 1, half = blk & 1;
    const int ch = pair >> 6, b = pair & 63;
    const int* sent = ch ? sent2 : sent1;
    const int w = tid >> 6, lane = tid & 63, quad = lane >> 4, l15 = lane & 15;

    // ---- embedding gather: 32 tokens x 40 k-octets = 1280 slots ----
    {
        float ef[2][8];
        int est[2], eso[2];
#pragma unroll
        for (int i = 0; i < 2; ++i) {
            int slot = i * 1024 + tid;
            est[i] = -1;
            if (slot < 1280) {
                int tloc = slot / 40, oct = slot - tloc * 40;
                est[i] = tloc; eso[i] = oct;
                int sid = sent[b * LL + half * 32 + tloc];   // direct, L1-broadcast
                const float* src = (sid >= 0) ? (wemb + (size_t)sid * EE) : unk;
                int k0 = oct * 8;
                if (k0 + 8 <= EE) {
                    f32x4 x0 = *(const f32x4*)(src + k0);
                    f32x4 x1 = *(const f32x4*)(src + k0 + 4);
                    ef[i][0]=x0[0]; ef[i][1]=x0[1]; ef[i][2]=x0[2]; ef[i][3]=x0[3];
                    ef[i][4]=x1[0]; ef[i][5]=x1[1]; ef[i][6]=x1[2]; ef[i][7]=x1[3];
                } else {
#pragma unroll
                    for (int j = 0; j < 8; ++j) ef[i][j] = (k0 + j < EE) ? src[k0 + j] : 0.f;
                }
            }
        }
#pragma unroll
        for (int i = 0; i < 2; ++i) {
            if (est[i] >= 0) {
                int tloc = est[i], oct = eso[i];
                short8 v;
#pragma unroll
                for (int j = 0; j < 8; ++j) v[j] = (short)f2bf(ef[i][j]);
                *(short8*)(AsL + (((tloc >> 4) * 10 + (oct >> 2)) * 64
                                  + ((oct & 3) << 4) + (tloc & 15)) * 8) = v;
            }
        }
    }
    __syncthreads();

    // ---- leaf GEMM: wave = (mt2, nu); B tiles {nu, nu+24, nu+32} = i,o,u ----
    const int mt2 = w & 1, nu = w >> 1;
    f32x4 acc[3] = {};
    short8 bb0[3], bb1[3];
#define LDW(dst, kkv) do { \
    dst[0] = *(const short8*)(WTB + ((size_t)((nu +  0) * 10 + (kkv)) * 64 + lane) * 8); \
    dst[1] = *(const short8*)(WTB + ((size_t)((nu + 24) * 10 + (kkv)) * 64 + lane) * 8); \
    dst[2] = *(const short8*)(WTB + ((size_t)((nu + 32) * 10 + (kkv)) * 64 + lane) * 8); \
} while (0)
    LDW(bb0, 0);
#pragma unroll 1
    for (int kk = 0; kk < 10; kk += 2) {
        LDW(bb1, kk + 1);
        short8 a0 = *(const short8*)(AsL + ((mt2 * 10 + kk) * 64 + lane) * 8);
        acc[0] = __builtin_amdgcn_mfma_f32_16x16x32_bf16(a0, bb0[0], acc[0], 0, 0, 0);
        acc[1] = __builtin_amdgcn_mfma_f32_16x16x32_bf16(a0, bb0[1], acc[1], 0, 0, 0);
        acc[2] = __builtin_amdgcn_mfma_f32_16x16x32_bf16(a0, bb0[2], acc[2], 0, 0, 0);
        if (kk + 2 < 10) LDW(bb0, kk + 2);
        short8 a1 = *(const short8*)(AsL + ((mt2 * 10 + kk + 1) * 64 + lane) * 8);
        acc[0] = __builtin_amdgcn_mfma_f32_16x16x32_bf16(a1, bb1[0], acc[0], 0, 0, 0);
        acc[1] = __builtin_amdgcn_mfma_f32_16x16x32_bf16(a1, bb1[1], acc[1], 0, 0, 0);
        acc[2] = __builtin_amdgcn_mfma_f32_16x16x32_bf16(a1, bb1[2], acc[2], 0, 0, 0);
    }
#undef LDW

    {
        int jc = nu * 16 + l15;
        float bi = bias[jc], bo = bias[3 * HH + jc], bu = bias[4 * HH + jc];
        size_t pb = (size_t)pair * 16384;    // 64 rows * 256
#pragma unroll
        for (int r = 0; r < 4; ++r) {
            float cv = sigf(acc[0][r] + bi) * tanhf(acc[2][r] + bu);
            float hv = sigf(acc[1][r] + bo) * tanhf(cv);
            int l = half * 32 + mt2 * 16 + quad * 4 + r;
            chartG[pb + (size_t)l * 256 + jc]      = (short)f2bf(cv);
            chartG[pb + (size_t)l * 256 + HH + jc] = (short)f2bf(hv);
        }
    }
}

// ---------------------------------------------------------------------------
// Step kernel: 128 blocks x 1024 threads, one (chart,batch) pair per block.
// Round-3 structure (all loads up front, register-built masks, wave-parallel
// closure, no spill) but U B-fragments come from packed UTB (lane-contiguous
// 16 B loads = coalesced), removing the TCP transaction-rate stall that
// dominated round 3 (82K L2 transactions/CU from 1 KB/lane row strides).
// ---------------------------------------------------------------------------
__global__ void __launch_bounds__(1024, 4) step_kernel(
        const int* __restrict__ ops1, const int* __restrict__ ops2,
        const int* __restrict__ oopl1, const int* __restrict__ oopl2,
        const short* __restrict__ UTB, const float* __restrict__ bias,
        const float* __restrict__ eu, const float* __restrict__ invt,
        const short* __restrict__ chartG, float* __restrict__ fin) {
    __shared__ __align__(16) short chartL[127 * CROW + 16];   // 69.1 KiB bf16 chart
    __shared__ __align__(16) short As2[2 * 8 * 64 * 8];       // 16 KiB step A-frags
    __shared__ __align__(16) float chh[32 * 132];             // 16.9 KiB
    __shared__ __align__(16) int ops_all[SS * 64];            // 16.1 KiB
    __shared__ unsigned long long smask[64];
    __shared__ int live_list[SS];
    __shared__ float e_num[AMB], h2s[AMB], s_w[AMB];
    __shared__ float comb[2][2][HH];
    __shared__ int nl_sh;
    __shared__ float un_sh;

    const int tid = threadIdx.x;
    const int pair = blockIdx.x, ch = pair >> 6, b = pair & 63;
    const int* ops  = ch ? ops2 : ops1;
    const int* oopl = ch ? oopl2 : oopl1;
    const float it = invt[0];
    const int w = tid >> 6, lane = tid & 63, quad = lane >> 4, l15 = lane & 15;

    // ---- issue ALL independent global loads up front ----
    const int4* cg = (const int4*)(chartG + (size_t)pair * 16384);
    int4 c0 = cg[tid];
    int4 c1 = cg[1024 + tid];
    int4 opv = make_int4(0, 0, 0, 0);
    if (tid < 1008) opv = ((const int4*)(ops + (size_t)b * SS * 64))[tid];
    if (tid < 64) {
        float v = eu[tid] * eu[tid] + eu[tid + 64] * eu[tid + 64];
        for (int off = 32; off >= 1; off >>= 1) v += __shfl_xor(v, off);
        if (tid == 0) un_sh = fmaxf(sqrtf(v), 1e-8f);
    }
    // zero step rows (independent of loads)
#pragma unroll
    for (int i = 0; i < 3; ++i) {
        int idx = i * 1024 + tid;
        if (idx < 2142)   // 63 rows x 272 shorts = 2142 int4
            ((int4*)(chartL + 64 * CROW))[idx] = make_int4(0, 0, 0, 0);
    }
    // store leaf rows into LDS chart (row stride CROW)
    {
        int r0 = tid >> 5, cq0 = tid & 31;
        *(int4*)(chartL + r0 * CROW + (cq0 << 3)) = c0;
        int t2 = 1024 + tid;
        int r1 = t2 >> 5, cq1 = t2 & 31;
        *(int4*)(chartL + r1 * CROW + (cq1 << 3)) = c1;
    }
    // clamp + store ops; build per-step masks from registers
    {
        opv.x = min(max(opv.x, 0), PP - 1);
        opv.y = min(max(opv.y, 0), PP - 1);
        opv.z = min(max(opv.z, 0), PP - 1);
        opv.w = min(max(opv.w, 0), PP - 1);
        if (tid < 1008) ((int4*)ops_all)[tid] = opv;

        int t = tid >> 4;            // 16 threads (one int4 each) per step row
        unsigned long long bit = 0ull;
        if (tid < 1008) {
            int q;
            q = opv.x - LL; if (q >= 0 && q < t) bit |= 1ull << q;
            q = opv.y - LL; if (q >= 0 && q < t) bit |= 1ull << q;
            q = opv.z - LL; if (q >= 0 && q < t) bit |= 1ull << q;
            q = opv.w - LL; if (q >= 0 && q < t) bit |= 1ull << q;
        }
        bit |= __shfl_xor(bit, 1);
        bit |= __shfl_xor(bit, 2);
        bit |= __shfl_xor(bit, 4);
        bit |= __shfl_xor(bit, 8);
        if ((lane & 15) == 0 && t < SS) smask[t] = bit;
    }
    __syncthreads();

    // ---- wave-parallel transitive closure (wave 0) ----
    if (w == 0) {
        unsigned long long my = (lane < SS) ? smask[lane] : 0ull;
        unsigned long long m = 0ull;
        int q0 = oopl[b] - 1 - LL;
        if (q0 >= 0) { if (q0 > SS - 1) q0 = SS - 1; m = 1ull << q0; }
        while (true) {
            unsigned long long c = ((m >> lane) & 1ull) ? my : 0ull;
            for (int off = 32; off >= 1; off >>= 1) c |= __shfl_xor(c, off);
            unsigned long long nm = m | c;
            if (nm == m) break;
            m = nm;
        }
        if (lane == 0) {
            int n = 0;
            for (int t = 0; t < SS; ++t)
                if ((m >> t) & 1) live_list[n++] = t;
            nl_sh = n;
        }
    }
    __syncthreads();

    // ---- live steps (all LDS; packed UTB B-frags, coalesced) ----
    const int nl = nl_sh;
    const float eul = eu[lane], euh = eu[64 + lane];
    const int smt = w & 1, snu = w >> 1;
    const int sjc = snu * 16 + l15;
    const float bi  = bias[sjc],          bfl = bias[HH + sjc];
    const float bfr = bias[2 * HH + sjc], bo  = bias[3 * HH + sjc];
    const float bu  = bias[4 * HH + sjc];

    for (int sidx = 0; sidx < nl; ++sidx) {
        const int t = live_list[sidx];
        const int* oprow = ops_all + t * 64;

        // gather h -> step A-frags (pure LDS->LDS b128)
        {
            int a = tid >> 5, oct = tid & 31, side = oct >> 4, m8 = oct & 15;
            int row = oprow[2 * a + side];
            short8 v = *(const short8*)(chartL + row * CROW + HH + m8 * 8);
            *(short8*)(As2 + (((a >> 4) * 8 + (oct >> 2)) * 64
                              + ((oct & 3) << 4) + (a & 15)) * 8) = v;
        }
        __syncthreads();

        float cvals[4], hvals[4];
        {
            f32x4 acc[5] = {};
            for (int kk = 0; kk < 8; ++kk) {
                short8 a0 = *(const short8*)(As2 + ((smt * 8 + kk) * 64 + lane) * 8);
#pragma unroll
                for (int s5 = 0; s5 < 5; ++s5) {
                    short8 bv = *(const short8*)(UTB + ((size_t)((snu + 8 * s5) * 8 + kk) * 64 + lane) * 8);
                    acc[s5] = __builtin_amdgcn_mfma_f32_16x16x32_bf16(a0, bv, acc[s5], 0, 0, 0);
                }
            }
#pragma unroll
            for (int r = 0; r < 4; ++r) {
                int a = smt * 16 + quad * 4 + r;
                float ccLv = bf2f(chartL[oprow[2 * a] * CROW + sjc]);
                float ccRv = bf2f(chartL[oprow[2 * a + 1] * CROW + sjc]);
                float cv = sigf(acc[1][r] + bfl) * ccLv
                         + sigf(acc[2][r] + bfr) * ccRv
                         + sigf(acc[0][r] + bi) * tanhf(acc[4][r] + bu);
                float hv = sigf(acc[3][r] + bo) * tanhf(cv);
                cvals[r] = cv; hvals[r] = hv;
                chh[a * 132 + sjc] = hv;
            }
        }
        __syncthreads();

        // energy per candidate (16 waves x 2 cands)
#pragma unroll
        for (int i = 0; i < 2; ++i) {
            int a = w * 2 + i;
            float h0 = chh[a * 132 + lane], h1 = chh[a * 132 + 64 + lane];
            float pe = h0 * eul + h1 * euh;
            float pn = h0 * h0 + h1 * h1;
            for (int off = 32; off >= 1; off >>= 1) {
                pe += __shfl_xor(pe, off);
                pn += __shfl_xor(pn, off);
            }
            if (lane == 0) { e_num[a] = pe; h2s[a] = pn; }
        }
        __syncthreads();

        // softmax over 32 candidates (wave 0)
        if (tid < 64) {
            float v = (tid < AMB)
                ? (e_num[tid] / (fmaxf(sqrtf(h2s[tid]), 1e-8f) * un_sh)) * it
                : -3.4e38f;
            float m = v;
            for (int off = 32; off >= 1; off >>= 1) m = fmaxf(m, __shfl_xor(m, off));
            float ex = (tid < AMB) ? __expf(v - m) : 0.f;
            float su = ex;
            for (int off = 32; off >= 1; off >>= 1) su += __shfl_xor(su, off);
            if (tid < AMB) s_w[tid] = ex / su;
        }
        __syncthreads();

        // combine from registers, reduce across quads, write chart row L+t
        {
            float sc = 0.f, sh = 0.f;
#pragma unroll
            for (int r = 0; r < 4; ++r) {
                int a = smt * 16 + quad * 4 + r;
                float sw = s_w[a];
                sc = fmaf(sw, cvals[r], sc);
                sh = fmaf(sw, hvals[r], sh);
            }
            sc += __shfl_xor(sc, 16); sc += __shfl_xor(sc, 32);
            sh += __shfl_xor(sh, 16); sh += __shfl_xor(sh, 32);
            if (lane < 16) {
                comb[smt][0][sjc] = sc;
                comb[smt][1][sjc] = sh;
            }
        }
        __syncthreads();
        if (tid < K2) {
            int part = tid >> 7, col = tid & 127;
            float val = comb[0][part][col] + comb[1][part][col];
            chartL[(LL + t) * CROW + part * HH + col] = (short)f2bf(val);
        }
        __syncthreads();
    }

    // ---- final readout row -> global ----
    int p = min(max(oopl[b] - 1, 0), PP - 1);
    if (tid < K2)
        fin[(size_t)pair * K2 + tid] = bf2f(chartL[p * CROW + tid]);
}

// ---------------------------------------------------------------------------
// MLP readout: 256 blocks = 16 j-tiles x 16 b-tiles (4 batch rows each).
// ---------------------------------------------------------------------------
__global__ void __launch_bounds__(256) mlp_kernel(
        const float* __restrict__ fin,
        const float* __restrict__ A, const float* __restrict__ abias,
        float* __restrict__ out) {
    __shared__ __align__(16) float conc[4][512];
    const int tid = threadIdx.x;
    const int jt = blockIdx.x & 15, bt = blockIdx.x >> 4;

#pragma unroll
    for (int i = 0; i < 2; ++i) {
        int s = i * 256 + tid;                // 512 vec4 slots = 4 b x 128
        int bl = s >> 7, kv = s & 127;
        int k0 = kv * 4, sel = k0 >> 7, kk0 = k0 & 127;
        int b = bt * 4 + bl;
        f32x4 s1 = *(const f32x4*)(fin + (size_t)b * K2 + HH + kk0);
        f32x4 s2 = *(const f32x4*)(fin + (size_t)(BSZ + b) * K2 + HH + kk0);
        f32x4 v;
        if (sel == 0)      { f32x4 d = s1 - s2; v = d * d; }
        else if (sel == 1) v = s1 * s2;
        else if (sel == 2) v = s1;
        else               v = s2;
        *(f32x4*)&conc[bl][k0] = v;
    }
    __syncthreads();

    const int jj = tid & 63, bg = tid >> 6;
    const int j = jt * 64 + jj, b = bt * 4 + bg;
    const float* Arow = A + (size_t)j * 512;
    float acc0 = abias[j], acc1 = 0.f;
    for (int k = 0; k < 512; k += 8) {
        f32x4 a0 = *(const f32x4*)(Arow + k);
        f32x4 a1 = *(const f32x4*)(Arow + k + 4);
        f32x4 c0 = *(const f32x4*)&conc[bg][k];
        f32x4 c1 = *(const f32x4*)&conc[bg][k + 4];
#pragma unroll
        for (int u = 0; u < 4; ++u) {
            acc0 = fmaf(a0[u], c0[u], acc0);
            acc1 = fmaf(a1[u], c1[u], acc1);
        }
    }
    out[(size_t)b * MLPN + j] = fmaxf(acc0 + acc1, 0.f);
}

// ---------------------------------------------------------------------------
extern "C" void kernel_launch(void* const* d_in, const int* in_sizes, int n_in,
                              void* d_out, int out_size, void* d_ws, size_t ws_size,
                              hipStream_t stream) {
    const int*   sent1 = (const int*)d_in[0];
    const int*   ops1  = (const int*)d_in[1];
    const int*   oopl1 = (const int*)d_in[2];
    const int*   sent2 = (const int*)d_in[3];
    const int*   ops2  = (const int*)d_in[4];
    const int*   oopl2 = (const int*)d_in[5];
    const float* W     = (const float*)d_in[6];
    const float* U     = (const float*)d_in[7];
    const float* bias  = (const float*)d_in[8];
    const float* eu    = (const float*)d_in[9];
    const float* unk   = (const float*)d_in[10];
    const float* wemb  = (const float*)d_in[11];
    const float* A     = (const float*)d_in[12];
    const float* ab    = (const float*)d_in[13];
    const float* invt  = (const float*)d_in[14];
    float* out = (float*)d_out;
    (void)in_sizes; (void)n_in; (void)out_size; (void)ws_size;

    char* ws = (char*)d_ws;
    // ws layout (bytes):
    const size_t WTB_OFF = 0;            // 25600*16 = 409,600
    const size_t UTB_OFF = 409600;       // 20480*16 = 327,680
    const size_t CHG_OFF = 737280;       // 128*64*256*2 = 4,194,304
    const size_t FIN_OFF = 4931584;      // 128*256*4 = 131,072  (end 5,062,656)
    short* WTB    = (short*)(ws + WTB_OFF);
    short* UTB    = (short*)(ws + UTB_OFF);
    short* chartG = (short*)(ws + CHG_OFF);
    float* fin    = (float*)(ws + FIN_OFF);

    // prep (coalesced reads, scattered 16 B writes): 180 blocks
    prep_kernel<<<180, 256, 0, stream>>>(W, U, WTB, UTB);

    // leaf phase on ALL 256 CUs (packed WTB)
    leaf_kernel<<<256, 1024, 0, stream>>>(sent1, sent2, WTB, bias, unk, wemb, chartG);

    // step phase: 128 blocks (packed UTB)
    step_kernel<<<128, 1024, 0, stream>>>(ops1, ops2, oopl1, oopl2,
                                          UTB, bias, eu, invt, chartG, fin);

    mlp_kernel<<<256, 256, 0, stream>>>(fin, A, ab, out);
}